// Round 1
// baseline (1531.975 us; speedup 1.0000x reference)
//
#include <hip/hip_runtime.h>
#include <hip/hip_bf16.h>
#include <math.h>

// Problem constants
// L=1024, BT=64, D=768, HID=192, NH=4, hd=48, K=5, Hh=Ww=32, T=16
// Rows M = L*BT = 65536 everywhere.
//
// Pipeline:
//  1. xs0   = x @ fc1_w.T + fc1_b                         (65536 x 192), rows m = l*64+b
//  2. a     = xs0 @ convA_w.T + convA_b                   (65536 x 64)
//  3. bconv = a @ convB_w.T + convB_b                     (65536 x 192)
//  4. fuse: g = gelu(bconv+xs0); xs_sp[b*1024+l] = g; ln_sp = LN(g)   (spatial rows)
//  5. qkv   = ln_sp @ qkv_w.T + qkv_b                     (65536 x 576), spatial rows
//  6. natten: o = attention(qkv, rpb)                     (65536 x 192), spatial rows
//  7. y     = o @ proj_w.T + proj_b + xs_sp               (65536 x 192), spatial rows
//  8. out   = scatter(y @ fc2_w.T + fc2_b + x)            permuted (4,768,16,32,32)
//
// Workspace (floats): qkvR [37748736] | xs_sp [12582912] | ln_sp [12582912]
//   total = 62,914,560 floats = 251.7 MB
//   aliases: xs0 = qkvR+0, bconv = qkvR+12582912, a = qkvR+25165824,
//            qkv = qkvR (after xs0/bconv/a dead), o = ln_sp region (after ln dead),
//            y = qkvR (after qkv dead)

#define BM 64
#define BN 64
#define BK 16

__global__ __launch_bounds__(256) void gemm_kernel(
    const float* __restrict__ A, const float* __restrict__ W,
    const float* __restrict__ bias, const float* __restrict__ res,
    const float* __restrict__ xin, float* __restrict__ C,
    int M, int N, int K, int mode) {
  __shared__ float As[BK][BM + 1];
  __shared__ float Bs[BK][BN + 1];
  const int tid = threadIdx.x;
  const int tx = tid & 15;        // n direction (4 cols each)
  const int ty = tid >> 4;        // m direction (4 rows each)
  const int bm0 = blockIdx.y * BM;
  const int bn0 = blockIdx.x * BN;

  float acc[4][4] = {};

  for (int k0 = 0; k0 < K; k0 += BK) {
#pragma unroll
    for (int q = 0; q < 4; ++q) {
      int idx = tid + q * 256;          // 0..1023
      int mm = idx >> 4;                // 0..63
      int kk = idx & 15;                // 0..15
      As[kk][mm] = A[(size_t)(bm0 + mm) * K + (k0 + kk)];
      Bs[kk][mm] = W[(size_t)(bn0 + mm) * K + (k0 + kk)];
    }
    __syncthreads();
#pragma unroll
    for (int kk = 0; kk < BK; ++kk) {
      float av[4], bv[4];
#pragma unroll
      for (int q = 0; q < 4; ++q) av[q] = As[kk][ty * 4 + q];
#pragma unroll
      for (int q = 0; q < 4; ++q) bv[q] = Bs[kk][tx * 4 + q];
#pragma unroll
      for (int u = 0; u < 4; ++u)
#pragma unroll
        for (int v = 0; v < 4; ++v) acc[u][v] += av[u] * bv[v];
    }
    __syncthreads();
  }

#pragma unroll
  for (int u = 0; u < 4; ++u) {
    int m = bm0 + ty * 4 + u;
#pragma unroll
    for (int v = 0; v < 4; ++v) {
      int n = bn0 + tx * 4 + v;
      float val = acc[u][v] + bias[n];
      if (mode == 1) {
        val += res[(size_t)m * N + n];
        C[(size_t)m * N + n] = val;
      } else if (mode == 2) {
        // rows are spatial order: m = b*1024 + l
        int b = m >> 10;
        int ll = m & 1023;
        val += xin[((size_t)((ll << 6) | b)) * 768 + n];
        // out[g, n, t, h, w] with g=b>>4, t=b&15, l=h*32+w
        size_t off = (((size_t)(b >> 4) * 768 + n) * 16 + (b & 15)) * 1024 + ll;
        C[off] = val;
      } else {
        C[(size_t)m * N + n] = val;
      }
    }
  }
}

// GeLU(exact) + residual + transpose to spatial + LayerNorm. One wave per row.
__global__ __launch_bounds__(64) void fuse_gelu_ln_kernel(
    const float* __restrict__ bconv, const float* __restrict__ xs0,
    const float* __restrict__ ln_g, const float* __restrict__ ln_b,
    float* __restrict__ xs_sp, float* __restrict__ ln_sp) {
  const int r = blockIdx.x;        // m = l*64 + b
  const int l = r >> 6;
  const int b = r & 63;
  const int tid = threadIdx.x;
  const size_t src = (size_t)r * 192;
  const size_t dst = (size_t)((b << 10) | l) * 192;

  float g[3];
  float s1 = 0.0f, s2 = 0.0f;
#pragma unroll
  for (int q = 0; q < 3; ++q) {
    int c = tid + q * 64;
    float v = bconv[src + c] + xs0[src + c];
    float ge = 0.5f * v * (1.0f + erff(v * 0.70710678118654752f));
    g[q] = ge;
    s1 += ge;
    s2 += ge * ge;
  }
#pragma unroll
  for (int off = 32; off; off >>= 1) {
    s1 += __shfl_xor(s1, off);
    s2 += __shfl_xor(s2, off);
  }
  float mean = s1 * (1.0f / 192.0f);
  float var = s2 * (1.0f / 192.0f) - mean * mean;
  float rstd = rsqrtf(var + 1e-5f);
#pragma unroll
  for (int q = 0; q < 3; ++q) {
    int c = tid + q * 64;
    xs_sp[dst + c] = g[q];
    ln_sp[dst + c] = (g[q] - mean) * rstd * ln_g[c] + ln_b[c];
  }
}

// Neighborhood attention: one wave per pixel, 4 heads serially.
__global__ __launch_bounds__(64) void natten_kernel(
    const float* __restrict__ qkv, const float* __restrict__ rpb,
    float* __restrict__ o) {
  const int pix = blockIdx.x;      // b*1024 + l
  const int b = pix >> 10;
  const int l = pix & 1023;
  const int i = l >> 5;
  const int j = l & 31;
  const int tid = threadIdx.x;

  __shared__ float q_s[192];
  __shared__ float a_s[25];
  __shared__ int nrow[25];

  const float scale = 0.14433756729740643f;  // 1/sqrt(48)
  const float* qrow = qkv + (size_t)pix * 576;
#pragma unroll
  for (int c = tid; c < 192; c += 64) q_s[c] = qrow[c] * scale;

  int bh = 0, bw = 0;
  if (tid < 25) {
    int x = tid / 5, y = tid % 5;
    int ihc = min(max(i - 2, 0), 27);
    int iwc = min(max(j - 2, 0), 27);
    int ih = ihc + x;
    int iw = iwc + y;
    nrow[tid] = (b << 10) + (ih << 5) + iw;
    bh = ih - i + 4;                // in [0,8]
    bw = iw - j + 4;
  }
  __syncthreads();

  for (int n = 0; n < 4; ++n) {
    float s = -INFINITY;
    if (tid < 25) {
      const float* kp = qkv + (size_t)nrow[tid] * 576 + 192 + n * 48;
      const float* qp = q_s + n * 48;
      float acc = 0.0f;
#pragma unroll
      for (int d = 0; d < 48; ++d) acc += qp[d] * kp[d];
      acc += rpb[n * 81 + bh * 9 + bw];
      s = acc;
    }
    // softmax over the 25 valid lanes
    float m = s;
#pragma unroll
    for (int off = 32; off; off >>= 1) m = fmaxf(m, __shfl_xor(m, off));
    float e = (tid < 25) ? expf(s - m) : 0.0f;
    float sum = e;
#pragma unroll
    for (int off = 32; off; off >>= 1) sum += __shfl_xor(sum, off);
    if (tid < 25) a_s[tid] = e / sum;
    __syncthreads();

    if (tid < 48) {
      float acc = 0.0f;
#pragma unroll
      for (int s2 = 0; s2 < 25; ++s2) {
        acc += a_s[s2] * qkv[(size_t)nrow[s2] * 576 + 384 + n * 48 + tid];
      }
      o[(size_t)pix * 192 + n * 48 + tid] = acc;
    }
    __syncthreads();
  }
}

extern "C" void kernel_launch(void* const* d_in, const int* in_sizes, int n_in,
                              void* d_out, int out_size, void* d_ws, size_t ws_size,
                              hipStream_t stream) {
  const float* x       = (const float*)d_in[0];
  const float* fc1_w   = (const float*)d_in[1];
  const float* fc1_b   = (const float*)d_in[2];
  const float* convA_w = (const float*)d_in[3];
  const float* convA_b = (const float*)d_in[4];
  const float* convB_w = (const float*)d_in[5];
  const float* convB_b = (const float*)d_in[6];
  const float* ln_g    = (const float*)d_in[7];
  const float* ln_b    = (const float*)d_in[8];
  const float* qkv_w   = (const float*)d_in[9];
  const float* qkv_b   = (const float*)d_in[10];
  const float* rpb     = (const float*)d_in[11];
  const float* proj_w  = (const float*)d_in[12];
  const float* proj_b  = (const float*)d_in[13];
  const float* fc2_w   = (const float*)d_in[14];
  const float* fc2_b   = (const float*)d_in[15];
  float* out = (float*)d_out;

  const int M = 65536;
  const size_t R1 = 12582912;      // 65536*192

  float* ws    = (float*)d_ws;
  float* qkvR  = ws;               // 37748736 floats
  float* xs_sp = ws + 37748736;    // 12582912
  float* ln_sp = ws + 50331648;    // 12582912

  float* xs0   = qkvR;
  float* bconv = qkvR + R1;
  float* abuf  = qkvR + 2 * R1;
  float* qkv   = qkvR;
  float* obuf  = ln_sp;            // reuse after LN consumed
  float* ybuf  = qkvR;             // reuse after qkv consumed

  // 1. fc1: (65536 x 768) @ (192 x 768)^T
  gemm_kernel<<<dim3(192 / BN, M / BM), 256, 0, stream>>>(
      x, fc1_w, fc1_b, nullptr, nullptr, xs0, M, 192, 768, 0);
  // 2. convA: K=192, N=64
  gemm_kernel<<<dim3(64 / BN, M / BM), 256, 0, stream>>>(
      xs0, convA_w, convA_b, nullptr, nullptr, abuf, M, 64, 192, 0);
  // 3. convB: K=64, N=192
  gemm_kernel<<<dim3(192 / BN, M / BM), 256, 0, stream>>>(
      abuf, convB_w, convB_b, nullptr, nullptr, bconv, M, 192, 64, 0);
  // 4. gelu + residual + transpose + layernorm
  fuse_gelu_ln_kernel<<<M, 64, 0, stream>>>(bconv, xs0, ln_g, ln_b, xs_sp, ln_sp);
  // 5. qkv: K=192, N=576
  gemm_kernel<<<dim3(576 / BN, M / BM), 256, 0, stream>>>(
      ln_sp, qkv_w, qkv_b, nullptr, nullptr, qkv, M, 576, 192, 0);
  // 6. neighborhood attention
  natten_kernel<<<M, 64, 0, stream>>>(qkv, rpb, obuf);
  // 7. proj + residual(xs_sp)
  gemm_kernel<<<dim3(192 / BN, M / BM), 256, 0, stream>>>(
      obuf, proj_w, proj_b, xs_sp, nullptr, ybuf, M, 192, 192, 1);
  // 8. fc2 + residual(x) + scatter to (4,768,16,32,32)
  gemm_kernel<<<dim3(768 / BN, M / BM), 256, 0, stream>>>(
      ybuf, fc2_w, fc2_b, nullptr, x, out, M, 768, 192, 2);
}

// Round 2
// 682.634 us; speedup vs baseline: 2.2442x; 2.2442x over previous
//
#include <hip/hip_runtime.h>
#include <hip/hip_bf16.h>
#include <math.h>

// L=1024, BT=64, D=768, HID=192, NH=4, hd=48, K=5, Hh=Ww=32, T=16, M=65536
//
// bf16 pipeline:
//  cvt: x -> x_bf, weights -> bf16
//  1. xs0   = x_bf @ fc1_w.T + b          (M x 192) bf16, rows m = l*64+b
//  2. a     = xs0 @ convA_w.T + b         (M x 64)  bf16
//  3. bconv = a @ convB_w.T + b           (M x 192) bf16
//  4. fuse: g = gelu(bconv+xs0); xs_sp[spatial]=g; ln_sp=LN(g)   bf16
//  5. qkv   = ln_sp @ qkv_w.T + b         (M x 576) bf16 spatial
//  6. natten -> o                         (M x 192) bf16 spatial
//  7. y     = o @ proj_w.T + b + xs_sp    (M x 192) bf16 spatial
//  8. out   = scatter(y @ fc2_w.T + b + x)  fp32 permuted (4,768,16,32,32)

typedef __attribute__((ext_vector_type(4))) float f32x4;
typedef __attribute__((ext_vector_type(8))) __bf16 bf16x8;
typedef const __attribute__((address_space(1))) void gv_t;
typedef __attribute__((address_space(3))) void lv_t;

#define GBM 128
#define GBN 64
#define GBK 64

// ---------------- MFMA GEMM: C = A @ W^T + bias (+epilogue) ----------------
// A: (M,K) bf16 row-major. W: (N,K) bf16 row-major. 128x64 tile, BK=64,
// 4 waves in 2x2, each wave 64x32 out = 4x2 mfma_16x16x32 frags.
// LDS: linear [row][k], staged via global_load_lds with pre-swizzled global
// source; ds_read uses matching XOR swizzle (byte ^= (row&7)<<4).
__global__ __launch_bounds__(256) void mfma_gemm_kernel(
    const __hip_bfloat16* __restrict__ A, const __hip_bfloat16* __restrict__ W,
    const float* __restrict__ bias, const __hip_bfloat16* __restrict__ res,
    const float* __restrict__ xin, void* __restrict__ Cout,
    int M, int N, int K, int mode) {
  __shared__ __hip_bfloat16 Asm[2][GBM * GBK];
  __shared__ __hip_bfloat16 Bsm[2][GBN * GBK];

  const int tid = threadIdx.x;
  const int lane = tid & 63;
  const int wave = tid >> 6;
  const int bm0 = blockIdx.y * GBM;
  const int bn0 = blockIdx.x * GBN;
  const int wm0 = (wave >> 1) * 64;
  const int wn0 = (wave & 1) * 32;

  const int l15 = lane & 15;
  const int l7 = lane & 7;
  const int lg = lane >> 4;

  f32x4 acc[4][2] = {};

  int aro[4], bro[2], ksw[2];
#pragma unroll
  for (int mi = 0; mi < 4; ++mi) aro[mi] = (wm0 + mi * 16 + l15) * (GBK * 2);
#pragma unroll
  for (int nj = 0; nj < 2; ++nj) bro[nj] = (wn0 + nj * 16 + l15) * (GBK * 2);
#pragma unroll
  for (int kk = 0; kk < 2; ++kk) ksw[kk] = ((lg * 16 + kk * 64) ^ (l7 << 4));

  const int nk = K / GBK;

  auto stage = [&](int buf, int k0) {
#pragma unroll
    for (int q = 0; q < 4; ++q) {
      int ci = tid + q * 256;            // 0..1023 : A chunks (16B each)
      int r = ci >> 3;                   // row 0..127
      int sc = (ci & 7) ^ (r & 7);       // pre-swizzled source chunk
      const __hip_bfloat16* src = A + (size_t)(bm0 + r) * K + (k0 + sc * 8);
      __builtin_amdgcn_global_load_lds((gv_t*)src, (lv_t*)&Asm[buf][ci * 8], 16, 0, 0);
    }
#pragma unroll
    for (int q = 0; q < 2; ++q) {
      int ci = tid + q * 256;            // 0..511 : B chunks
      int r = ci >> 3;                   // row 0..63
      int sc = (ci & 7) ^ (r & 7);
      const __hip_bfloat16* src = W + (size_t)(bn0 + r) * K + (k0 + sc * 8);
      __builtin_amdgcn_global_load_lds((gv_t*)src, (lv_t*)&Bsm[buf][ci * 8], 16, 0, 0);
    }
  };

  stage(0, 0);
  for (int kt = 0; kt < nk; ++kt) {
    const int cur = kt & 1;
    __syncthreads();                     // drains vmcnt: buf[cur] staged
    if (kt + 1 < nk) stage(cur ^ 1, (kt + 1) * GBK);
    const char* Ab = (const char*)&Asm[cur][0];
    const char* Bb = (const char*)&Bsm[cur][0];
#pragma unroll
    for (int kk = 0; kk < 2; ++kk) {
      bf16x8 af[4], bfr[2];
#pragma unroll
      for (int mi = 0; mi < 4; ++mi)
        af[mi] = *(const bf16x8*)(Ab + aro[mi] + ksw[kk]);
#pragma unroll
      for (int nj = 0; nj < 2; ++nj)
        bfr[nj] = *(const bf16x8*)(Bb + bro[nj] + ksw[kk]);
#pragma unroll
      for (int mi = 0; mi < 4; ++mi)
#pragma unroll
        for (int nj = 0; nj < 2; ++nj)
          acc[mi][nj] = __builtin_amdgcn_mfma_f32_16x16x32_bf16(
              af[mi], bfr[nj], acc[mi][nj], 0, 0, 0);
    }
  }

  float* Cf = (float*)Cout;
  __hip_bfloat16* Cb = (__hip_bfloat16*)Cout;
#pragma unroll
  for (int nj = 0; nj < 2; ++nj) {
    const int n = bn0 + wn0 + nj * 16 + l15;
    const float bi = bias[n];
#pragma unroll
    for (int mi = 0; mi < 4; ++mi) {
      const int mb = bm0 + wm0 + mi * 16 + lg * 4;
      f32x4 v = acc[mi][nj];
#pragma unroll
      for (int r = 0; r < 4; ++r) {
        const int m = mb + r;
        float val = v[r] + bi;
        if (mode == 0) {
          Cb[(size_t)m * N + n] = __float2bfloat16(val);
        } else if (mode == 1) {
          val += __bfloat162float(res[(size_t)m * N + n]);
          Cb[(size_t)m * N + n] = __float2bfloat16(val);
        } else {
          const int b = m >> 10, ll = m & 1023;
          val += xin[((size_t)((ll << 6) | b)) * 768 + n];
          Cf[(((size_t)(b >> 4) * 768 + n) * 16 + (b & 15)) * 1024 + ll] = val;
        }
      }
    }
  }
}

// ---------------- fp32 -> bf16 convert (vectorized) ----------------
__global__ __launch_bounds__(256) void cvt_kernel(
    const float* __restrict__ in, __hip_bfloat16* __restrict__ out, int n4) {
  int i = blockIdx.x * 256 + threadIdx.x;
  if (i >= n4) return;
  float4 v = ((const float4*)in)[i];
  union { unsigned short u[4]; uint2 d; } o;
  __hip_bfloat16 b0 = __float2bfloat16(v.x);
  __hip_bfloat16 b1 = __float2bfloat16(v.y);
  __hip_bfloat16 b2 = __float2bfloat16(v.z);
  __hip_bfloat16 b3 = __float2bfloat16(v.w);
  o.u[0] = *(unsigned short*)&b0; o.u[1] = *(unsigned short*)&b1;
  o.u[2] = *(unsigned short*)&b2; o.u[3] = *(unsigned short*)&b3;
  ((uint2*)out)[i] = o.d;
}

// ---------------- GeLU + residual + transpose + LayerNorm ----------------
// 4 rows per 256-thread block, one wave per row.
__global__ __launch_bounds__(256) void fuse_gelu_ln_kernel(
    const __hip_bfloat16* __restrict__ bconv, const __hip_bfloat16* __restrict__ xs0,
    const float* __restrict__ ln_g, const float* __restrict__ ln_b,
    __hip_bfloat16* __restrict__ xs_sp, __hip_bfloat16* __restrict__ ln_sp) {
  const int r = blockIdx.x * 4 + (threadIdx.x >> 6);  // m = l*64 + b
  const int tid = threadIdx.x & 63;
  const int l = r >> 6;
  const int b = r & 63;
  const size_t src = (size_t)r * 192;
  const size_t dst = (size_t)((b << 10) | l) * 192;

  float g[3];
  float s1 = 0.0f, s2 = 0.0f;
#pragma unroll
  for (int q = 0; q < 3; ++q) {
    int c = tid + q * 64;
    float v = __bfloat162float(bconv[src + c]) + __bfloat162float(xs0[src + c]);
    float ge = 0.5f * v * (1.0f + erff(v * 0.70710678118654752f));
    g[q] = ge;
    s1 += ge;
    s2 += ge * ge;
  }
#pragma unroll
  for (int off = 32; off; off >>= 1) {
    s1 += __shfl_xor(s1, off);
    s2 += __shfl_xor(s2, off);
  }
  float mean = s1 * (1.0f / 192.0f);
  float var = s2 * (1.0f / 192.0f) - mean * mean;
  float rstd = rsqrtf(var + 1e-5f);
#pragma unroll
  for (int q = 0; q < 3; ++q) {
    int c = tid + q * 64;
    xs_sp[dst + c] = __float2bfloat16(g[q]);
    ln_sp[dst + c] = __float2bfloat16((g[q] - mean) * rstd * ln_g[c] + ln_b[c]);
  }
}

// ---------------- Neighborhood attention ----------------
__global__ __launch_bounds__(64) void natten_kernel(
    const __hip_bfloat16* __restrict__ qkv, const float* __restrict__ rpb,
    __hip_bfloat16* __restrict__ o) {
  const int pix = blockIdx.x;  // b*1024 + l
  const int b = pix >> 10;
  const int l = pix & 1023;
  const int i = l >> 5;
  const int j = l & 31;
  const int tid = threadIdx.x;

  __shared__ float q_s[192];
  __shared__ float a_s[25];
  __shared__ int nrow[25];

  const float scale = 0.14433756729740643f;  // 1/sqrt(48)
  const __hip_bfloat16* qrow = qkv + (size_t)pix * 576;
#pragma unroll
  for (int c = tid; c < 192; c += 64) q_s[c] = __bfloat162float(qrow[c]) * scale;

  int bh = 0, bw = 0;
  if (tid < 25) {
    int x = tid / 5, y = tid % 5;
    int ih = min(max(i - 2, 0), 27) + x;
    int iw = min(max(j - 2, 0), 27) + y;
    nrow[tid] = (b << 10) + (ih << 5) + iw;
    bh = ih - i + 4;
    bw = iw - j + 4;
  }
  __syncthreads();

  for (int n = 0; n < 4; ++n) {
    float s = -INFINITY;
    if (tid < 25) {
      const bf16x8* kp = (const bf16x8*)(qkv + (size_t)nrow[tid] * 576 + 192 + n * 48);
      float acc = 0.0f;
#pragma unroll
      for (int t = 0; t < 6; ++t) {
        bf16x8 kv = kp[t];
#pragma unroll
        for (int u = 0; u < 8; ++u) acc += q_s[n * 48 + t * 8 + u] * (float)kv[u];
      }
      s = acc + rpb[n * 81 + bh * 9 + bw];
    }
    float m = s;
#pragma unroll
    for (int off = 32; off; off >>= 1) m = fmaxf(m, __shfl_xor(m, off));
    float e = (tid < 25) ? expf(s - m) : 0.0f;
    float sum = e;
#pragma unroll
    for (int off = 32; off; off >>= 1) sum += __shfl_xor(sum, off);
    if (tid < 25) a_s[tid] = e / sum;
    __syncthreads();

    if (tid < 48) {
      float acc = 0.0f;
#pragma unroll
      for (int s2 = 0; s2 < 25; ++s2)
        acc += a_s[s2] * __bfloat162float(qkv[(size_t)nrow[s2] * 576 + 384 + n * 48 + tid]);
      o[(size_t)pix * 192 + n * 48 + tid] = __float2bfloat16(acc);
    }
    __syncthreads();
  }
}

extern "C" void kernel_launch(void* const* d_in, const int* in_sizes, int n_in,
                              void* d_out, int out_size, void* d_ws, size_t ws_size,
                              hipStream_t stream) {
  const float* x       = (const float*)d_in[0];
  const float* fc1_w   = (const float*)d_in[1];
  const float* fc1_b   = (const float*)d_in[2];
  const float* convA_w = (const float*)d_in[3];
  const float* convA_b = (const float*)d_in[4];
  const float* convB_w = (const float*)d_in[5];
  const float* convB_b = (const float*)d_in[6];
  const float* ln_g    = (const float*)d_in[7];
  const float* ln_b    = (const float*)d_in[8];
  const float* qkv_w   = (const float*)d_in[9];
  const float* qkv_b   = (const float*)d_in[10];
  const float* rpb     = (const float*)d_in[11];
  const float* proj_w  = (const float*)d_in[12];
  const float* proj_b  = (const float*)d_in[13];
  const float* fc2_w   = (const float*)d_in[14];
  const float* fc2_b   = (const float*)d_in[15];
  float* out = (float*)d_out;

  const int M = 65536;
  char* W0 = (char*)d_ws;
  __hip_bfloat16* x_bf  = (__hip_bfloat16*)W0;                 // 50,331,648 elems
  __hip_bfloat16* wfc1  = (__hip_bfloat16*)(W0 + 100663296);
  __hip_bfloat16* wcvA  = wfc1 + 147456;
  __hip_bfloat16* wcvB  = wcvA + 12288;
  __hip_bfloat16* wqkv  = wcvB + 12288;
  __hip_bfloat16* wproj = wqkv + 110592;
  __hip_bfloat16* wfc2  = wproj + 36864;
  __hip_bfloat16* reg1  = wfc2 + 147456;                       // 37,748,736 elems
  __hip_bfloat16* xs0   = reg1;
  __hip_bfloat16* bconv = reg1 + 12582912;
  __hip_bfloat16* abuf  = reg1 + 25165824;
  __hip_bfloat16* qkvb  = reg1;
  __hip_bfloat16* ybuf  = reg1;
  __hip_bfloat16* xs_sp = reg1 + 37748736;                     // 12,582,912
  __hip_bfloat16* ln_sp = xs_sp + 12582912;                    // 12,582,912
  __hip_bfloat16* obuf  = ln_sp;                               // reuse after qkv GEMM

  auto cvt = [&](const float* in, __hip_bfloat16* outp, int n) {
    int n4 = n / 4;
    cvt_kernel<<<(n4 + 255) / 256, 256, 0, stream>>>(in, outp, n4);
  };
  cvt(x, x_bf, 50331648);
  cvt(fc1_w, wfc1, 147456);
  cvt(convA_w, wcvA, 12288);
  cvt(convB_w, wcvB, 12288);
  cvt(qkv_w, wqkv, 110592);
  cvt(proj_w, wproj, 36864);
  cvt(fc2_w, wfc2, 147456);

  // 1. fc1
  mfma_gemm_kernel<<<dim3(3, 512), 256, 0, stream>>>(
      x_bf, wfc1, fc1_b, nullptr, nullptr, xs0, M, 192, 768, 0);
  // 2. convA
  mfma_gemm_kernel<<<dim3(1, 512), 256, 0, stream>>>(
      xs0, wcvA, convA_b, nullptr, nullptr, abuf, M, 64, 192, 0);
  // 3. convB
  mfma_gemm_kernel<<<dim3(3, 512), 256, 0, stream>>>(
      abuf, wcvB, convB_b, nullptr, nullptr, bconv, M, 192, 64, 0);
  // 4. gelu + residual + transpose + LN
  fuse_gelu_ln_kernel<<<16384, 256, 0, stream>>>(bconv, xs0, ln_g, ln_b, xs_sp, ln_sp);
  // 5. qkv
  mfma_gemm_kernel<<<dim3(9, 512), 256, 0, stream>>>(
      ln_sp, wqkv, qkv_b, nullptr, nullptr, qkvb, M, 576, 192, 0);
  // 6. natten
  natten_kernel<<<65536, 64, 0, stream>>>(qkvb, rpb, obuf);
  // 7. proj + residual(xs_sp)
  mfma_gemm_kernel<<<dim3(3, 512), 256, 0, stream>>>(
      obuf, wproj, proj_b, xs_sp, nullptr, ybuf, M, 192, 192, 1);
  // 8. fc2 + residual(x) + permuted scatter
  mfma_gemm_kernel<<<dim3(12, 512), 256, 0, stream>>>(
      ybuf, wfc2, fc2_b, nullptr, x, (void*)out, M, 768, 192, 2);
}

// Round 3
// 522.815 us; speedup vs baseline: 2.9302x; 1.3057x over previous
//
#include <hip/hip_runtime.h>
#include <hip/hip_bf16.h>
#include <math.h>

// L=1024, BT=64, D=768, HID=192, NH=4, hd=48, K=5, Hh=Ww=32, T=16, M=65536
//
// bf16 pipeline:
//  cvt: x -> x_bf, weights -> bf16
//  1. xs0   = x_bf @ fc1_w.T + b          (M x 192) bf16, rows m = l*64+b
//  2. a     = xs0 @ convA_w.T + b         (M x 64)  bf16
//  3. bconv = a @ convB_w.T + b           (M x 192) bf16
//  4. fuse: g = gelu(bconv+xs0); xs_sp[spatial]=g; ln_sp=LN(g)   bf16
//  5. qkv   = ln_sp @ qkv_w.T + b         (M x 576) bf16 spatial
//  6. natten -> o                         (M x 192) bf16 spatial (1 px/lane)
//  7. y     = o @ proj_w.T + b + xs_sp    (M x 192) bf16 spatial
//  8. out   = scatter(y @ fc2_w.T + b + x)  fp32 permuted, SWAPPED mfma so
//     the 16-lane dim maps to ll (contiguous out dim) -> coalesced writes.

typedef __attribute__((ext_vector_type(4))) float f32x4;
typedef __attribute__((ext_vector_type(8))) __bf16 bf16x8;
typedef const __attribute__((address_space(1))) void gv_t;
typedef __attribute__((address_space(3))) void lv_t;

#define GBM 128
#define GBN 64
#define GBK 64

// ---------------- MFMA GEMM: C = A @ W^T + bias (+epilogue) ----------------
// MODE 0: C bf16. MODE 1: C = .. + res, bf16. MODE 2: swapped-operand MFMA,
// C fp32 scattered to (4,768,16,32,32) with + x residual (permuted read).
template <int MODE>
__global__ __launch_bounds__(256) void mfma_gemm_kernel(
    const __hip_bfloat16* __restrict__ A, const __hip_bfloat16* __restrict__ W,
    const float* __restrict__ bias, const __hip_bfloat16* __restrict__ res,
    const float* __restrict__ xin, void* __restrict__ Cout,
    int M, int N, int K) {
  __shared__ __hip_bfloat16 Asm[2][GBM * GBK];
  __shared__ __hip_bfloat16 Bsm[2][GBN * GBK];

  const int tid = threadIdx.x;
  const int lane = tid & 63;
  const int wave = tid >> 6;

  // chunked XCD swizzle (all grids have nwg % 8 == 0)
  const int gx = gridDim.x;
  const int nwg = gx * gridDim.y;
  int id = blockIdx.y * gx + blockIdx.x;
  id = (id & 7) * (nwg >> 3) + (id >> 3);
  const int bm0 = (id / gx) * GBM;
  const int bn0 = (id % gx) * GBN;

  const int wm0 = (wave >> 1) * 64;
  const int wn0 = (wave & 1) * 32;

  const int l15 = lane & 15;
  const int l7 = lane & 7;
  const int lg = lane >> 4;

  f32x4 acc[4][2] = {};

  int aro[4], bro[2], ksw[2];
#pragma unroll
  for (int mi = 0; mi < 4; ++mi) aro[mi] = (wm0 + mi * 16 + l15) * (GBK * 2);
#pragma unroll
  for (int nj = 0; nj < 2; ++nj) bro[nj] = (wn0 + nj * 16 + l15) * (GBK * 2);
#pragma unroll
  for (int kk = 0; kk < 2; ++kk) ksw[kk] = ((lg * 16 + kk * 64) ^ (l7 << 4));

  const int nk = K / GBK;

  auto stage = [&](int buf, int k0) {
#pragma unroll
    for (int q = 0; q < 4; ++q) {
      int ci = tid + q * 256;            // 0..1023 : A chunks (16B each)
      int r = ci >> 3;                   // row 0..127
      int sc = (ci & 7) ^ (r & 7);       // pre-swizzled source chunk
      const __hip_bfloat16* src = A + (size_t)(bm0 + r) * K + (k0 + sc * 8);
      __builtin_amdgcn_global_load_lds((gv_t*)src, (lv_t*)&Asm[buf][ci * 8], 16, 0, 0);
    }
#pragma unroll
    for (int q = 0; q < 2; ++q) {
      int ci = tid + q * 256;            // 0..511 : B chunks
      int r = ci >> 3;                   // row 0..63
      int sc = (ci & 7) ^ (r & 7);
      const __hip_bfloat16* src = W + (size_t)(bn0 + r) * K + (k0 + sc * 8);
      __builtin_amdgcn_global_load_lds((gv_t*)src, (lv_t*)&Bsm[buf][ci * 8], 16, 0, 0);
    }
  };

  stage(0, 0);
  for (int kt = 0; kt < nk; ++kt) {
    const int cur = kt & 1;
    __syncthreads();                     // drains vmcnt: buf[cur] staged
    if (kt + 1 < nk) stage(cur ^ 1, (kt + 1) * GBK);
    const char* Ab = (const char*)&Asm[cur][0];
    const char* Bb = (const char*)&Bsm[cur][0];
#pragma unroll
    for (int kk = 0; kk < 2; ++kk) {
      bf16x8 af[4], bfr[2];
#pragma unroll
      for (int mi = 0; mi < 4; ++mi)
        af[mi] = *(const bf16x8*)(Ab + aro[mi] + ksw[kk]);
#pragma unroll
      for (int nj = 0; nj < 2; ++nj)
        bfr[nj] = *(const bf16x8*)(Bb + bro[nj] + ksw[kk]);
#pragma unroll
      for (int mi = 0; mi < 4; ++mi)
#pragma unroll
        for (int nj = 0; nj < 2; ++nj) {
          if constexpr (MODE == 2)
            acc[mi][nj] = __builtin_amdgcn_mfma_f32_16x16x32_bf16(
                bfr[nj], af[mi], acc[mi][nj], 0, 0, 0);   // D[row=n][col=m]
          else
            acc[mi][nj] = __builtin_amdgcn_mfma_f32_16x16x32_bf16(
                af[mi], bfr[nj], acc[mi][nj], 0, 0, 0);   // D[row=m][col=n]
        }
    }
  }

  if constexpr (MODE == 2) {
    float* Cf = (float*)Cout;
#pragma unroll
    for (int nj = 0; nj < 2; ++nj) {
      const int n0 = bn0 + wn0 + nj * 16 + lg * 4;
      const f32x4 bi4 = *(const f32x4*)(bias + n0);
#pragma unroll
      for (int mi = 0; mi < 4; ++mi) {
        const int m = bm0 + wm0 + mi * 16 + l15;   // col = lane&15 -> m
        const int b = m >> 10;
        const int ll = m & 1023;
        const f32x4 xv = *(const f32x4*)(xin + (size_t)((ll << 6) | b) * 768 + n0);
        const size_t ob = (((size_t)(b >> 4) * 768 + n0) * 16 + (b & 15)) * 1024 + ll;
#pragma unroll
        for (int r = 0; r < 4; ++r) {
          Cf[ob + (size_t)r * 16384] = acc[mi][nj][r] + bi4[r] + xv[r];
        }
      }
    }
  } else {
    __hip_bfloat16* Cb = (__hip_bfloat16*)Cout;
#pragma unroll
    for (int nj = 0; nj < 2; ++nj) {
      const int n = bn0 + wn0 + nj * 16 + l15;
      const float bi = bias[n];
#pragma unroll
      for (int mi = 0; mi < 4; ++mi) {
        const int mb = bm0 + wm0 + mi * 16 + lg * 4;
        f32x4 v = acc[mi][nj];
#pragma unroll
        for (int r = 0; r < 4; ++r) {
          const int m = mb + r;
          float val = v[r] + bi;
          if constexpr (MODE == 1) val += __bfloat162float(res[(size_t)m * N + n]);
          Cb[(size_t)m * N + n] = __float2bfloat16(val);
        }
      }
    }
  }
}

// ---------------- fp32 -> bf16 convert (vectorized) ----------------
__global__ __launch_bounds__(256) void cvt_kernel(
    const float* __restrict__ in, __hip_bfloat16* __restrict__ out, int n4) {
  int i = blockIdx.x * 256 + threadIdx.x;
  if (i >= n4) return;
  float4 v = ((const float4*)in)[i];
  union { unsigned short u[4]; uint2 d; } o;
  __hip_bfloat16 b0 = __float2bfloat16(v.x);
  __hip_bfloat16 b1 = __float2bfloat16(v.y);
  __hip_bfloat16 b2 = __float2bfloat16(v.z);
  __hip_bfloat16 b3 = __float2bfloat16(v.w);
  o.u[0] = *(unsigned short*)&b0; o.u[1] = *(unsigned short*)&b1;
  o.u[2] = *(unsigned short*)&b2; o.u[3] = *(unsigned short*)&b3;
  ((uint2*)out)[i] = o.d;
}

// ---------------- GeLU + residual + transpose + LayerNorm ----------------
__global__ __launch_bounds__(256) void fuse_gelu_ln_kernel(
    const __hip_bfloat16* __restrict__ bconv, const __hip_bfloat16* __restrict__ xs0,
    const float* __restrict__ ln_g, const float* __restrict__ ln_b,
    __hip_bfloat16* __restrict__ xs_sp, __hip_bfloat16* __restrict__ ln_sp) {
  const int r = blockIdx.x * 4 + (threadIdx.x >> 6);  // m = l*64 + b
  const int tid = threadIdx.x & 63;
  const int l = r >> 6;
  const int b = r & 63;
  const size_t src = (size_t)r * 192;
  const size_t dst = (size_t)((b << 10) | l) * 192;

  float g[3];
  float s1 = 0.0f, s2 = 0.0f;
#pragma unroll
  for (int q = 0; q < 3; ++q) {
    int c = tid + q * 64;
    float v = __bfloat162float(bconv[src + c]) + __bfloat162float(xs0[src + c]);
    float ge = 0.5f * v * (1.0f + erff(v * 0.70710678118654752f));
    g[q] = ge;
    s1 += ge;
    s2 += ge * ge;
  }
#pragma unroll
  for (int off = 32; off; off >>= 1) {
    s1 += __shfl_xor(s1, off);
    s2 += __shfl_xor(s2, off);
  }
  float mean = s1 * (1.0f / 192.0f);
  float var = s2 * (1.0f / 192.0f) - mean * mean;
  float rstd = rsqrtf(var + 1e-5f);
#pragma unroll
  for (int q = 0; q < 3; ++q) {
    int c = tid + q * 64;
    xs_sp[dst + c] = __float2bfloat16(g[q]);
    ln_sp[dst + c] = __float2bfloat16((g[q] - mean) * rstd * ln_g[c] + ln_b[c]);
  }
}

// ---------------- Neighborhood attention: 1 pixel per lane ----------------
// 4 waves/block; each wave owns an 8x8 pixel tile. Per head: each lane
// computes its own 25 scores (K gathers hit L1: per-head halo ~14KB),
// in-register softmax, PV accumulation. All 64 lanes always active.
__global__ __launch_bounds__(256) void natten_kernel(
    const __hip_bfloat16* __restrict__ qkv, const float* __restrict__ rpb,
    __hip_bfloat16* __restrict__ o) {
  const int wid = threadIdx.x >> 6;
  const int lane = threadIdx.x & 63;
  const int tile = blockIdx.x * 4 + wid;       // 1024 tiles
  const int b = tile >> 4;
  const int ti = (tile >> 2) & 3;
  const int tj = tile & 3;
  const int i = ti * 8 + (lane >> 3);
  const int j = tj * 8 + (lane & 7);
  const int pix = (b << 10) + (i << 5) + j;
  const int ih0 = min(max(i - 2, 0), 27);
  const int iw0 = min(max(j - 2, 0), 27);
  const size_t base0 = (size_t)((b << 10) + (ih0 << 5) + iw0) * 576;
  const int dbh = ih0 - i + 4;
  const int dbw = iw0 - j + 4;
  const float scale = 0.14433756729740643f;    // 1/sqrt(48)
  const __hip_bfloat16* qr = qkv + (size_t)pix * 576;

#pragma unroll
  for (int h = 0; h < 4; ++h) {
    float q[48];
    const bf16x8* qp = (const bf16x8*)(qr + h * 48);
#pragma unroll
    for (int t = 0; t < 6; ++t) {
      bf16x8 v = qp[t];
#pragma unroll
      for (int u = 0; u < 8; ++u) q[t * 8 + u] = (float)v[u] * scale;
    }

    float s[25];
#pragma unroll
    for (int x = 0; x < 5; ++x) {
#pragma unroll
      for (int y = 0; y < 5; ++y) {
        const bf16x8* kp =
            (const bf16x8*)(qkv + base0 + (size_t)(x * 32 + y) * 576 + 192 + h * 48);
        float a = 0.0f;
#pragma unroll
        for (int t = 0; t < 6; ++t) {
          bf16x8 kv = kp[t];
#pragma unroll
          for (int u = 0; u < 8; ++u) a += q[t * 8 + u] * (float)kv[u];
        }
        s[x * 5 + y] = a + rpb[h * 81 + (dbh + x) * 9 + (dbw + y)];
      }
    }

    float mx = s[0];
#pragma unroll
    for (int n = 1; n < 25; ++n) mx = fmaxf(mx, s[n]);
    float sum = 0.0f;
#pragma unroll
    for (int n = 0; n < 25; ++n) {
      s[n] = __expf(s[n] - mx);
      sum += s[n];
    }
    const float inv = 1.0f / sum;

    float pv[48] = {};
#pragma unroll
    for (int x = 0; x < 5; ++x) {
#pragma unroll
      for (int y = 0; y < 5; ++y) {
        const bf16x8* vp =
            (const bf16x8*)(qkv + base0 + (size_t)(x * 32 + y) * 576 + 384 + h * 48);
        const float w = s[x * 5 + y];
#pragma unroll
        for (int t = 0; t < 6; ++t) {
          bf16x8 vv = vp[t];
#pragma unroll
          for (int u = 0; u < 8; ++u) pv[t * 8 + u] += w * (float)vv[u];
        }
      }
    }

    bf16x8* op = (bf16x8*)(o + (size_t)pix * 192 + h * 48);
#pragma unroll
    for (int t = 0; t < 6; ++t) {
      bf16x8 ov;
#pragma unroll
      for (int u = 0; u < 8; ++u) ov[u] = (__bf16)(pv[t * 8 + u] * inv);
      op[t] = ov;
    }
  }
}

extern "C" void kernel_launch(void* const* d_in, const int* in_sizes, int n_in,
                              void* d_out, int out_size, void* d_ws, size_t ws_size,
                              hipStream_t stream) {
  const float* x       = (const float*)d_in[0];
  const float* fc1_w   = (const float*)d_in[1];
  const float* fc1_b   = (const float*)d_in[2];
  const float* convA_w = (const float*)d_in[3];
  const float* convA_b = (const float*)d_in[4];
  const float* convB_w = (const float*)d_in[5];
  const float* convB_b = (const float*)d_in[6];
  const float* ln_g    = (const float*)d_in[7];
  const float* ln_b    = (const float*)d_in[8];
  const float* qkv_w   = (const float*)d_in[9];
  const float* qkv_b   = (const float*)d_in[10];
  const float* rpb     = (const float*)d_in[11];
  const float* proj_w  = (const float*)d_in[12];
  const float* proj_b  = (const float*)d_in[13];
  const float* fc2_w   = (const float*)d_in[14];
  const float* fc2_b   = (const float*)d_in[15];
  float* out = (float*)d_out;

  const int M = 65536;
  char* W0 = (char*)d_ws;
  __hip_bfloat16* x_bf  = (__hip_bfloat16*)W0;                 // 50,331,648 elems
  __hip_bfloat16* wfc1  = (__hip_bfloat16*)(W0 + 100663296);
  __hip_bfloat16* wcvA  = wfc1 + 147456;
  __hip_bfloat16* wcvB  = wcvA + 12288;
  __hip_bfloat16* wqkv  = wcvB + 12288;
  __hip_bfloat16* wproj = wqkv + 110592;
  __hip_bfloat16* wfc2  = wproj + 36864;
  __hip_bfloat16* reg1  = wfc2 + 147456;                       // 37,748,736 elems
  __hip_bfloat16* xs0   = reg1;
  __hip_bfloat16* bconv = reg1 + 12582912;
  __hip_bfloat16* abuf  = reg1 + 25165824;
  __hip_bfloat16* qkvb  = reg1;
  __hip_bfloat16* ybuf  = reg1;
  __hip_bfloat16* xs_sp = reg1 + 37748736;                     // 12,582,912
  __hip_bfloat16* ln_sp = xs_sp + 12582912;                    // 12,582,912
  __hip_bfloat16* obuf  = ln_sp;                               // reuse after qkv GEMM

  auto cvt = [&](const float* in, __hip_bfloat16* outp, int n) {
    int n4 = n / 4;
    cvt_kernel<<<(n4 + 255) / 256, 256, 0, stream>>>(in, outp, n4);
  };
  cvt(x, x_bf, 50331648);
  cvt(fc1_w, wfc1, 147456);
  cvt(convA_w, wcvA, 12288);
  cvt(convB_w, wcvB, 12288);
  cvt(qkv_w, wqkv, 110592);
  cvt(proj_w, wproj, 36864);
  cvt(fc2_w, wfc2, 147456);

  // 1. fc1
  mfma_gemm_kernel<0><<<dim3(3, 512), 256, 0, stream>>>(
      x_bf, wfc1, fc1_b, nullptr, nullptr, xs0, M, 192, 768);
  // 2. convA
  mfma_gemm_kernel<0><<<dim3(1, 512), 256, 0, stream>>>(
      xs0, wcvA, convA_b, nullptr, nullptr, abuf, M, 64, 192);
  // 3. convB
  mfma_gemm_kernel<0><<<dim3(3, 512), 256, 0, stream>>>(
      abuf, wcvB, convB_b, nullptr, nullptr, bconv, M, 192, 64);
  // 4. gelu + residual + transpose + LN
  fuse_gelu_ln_kernel<<<16384, 256, 0, stream>>>(bconv, xs0, ln_g, ln_b, xs_sp, ln_sp);
  // 5. qkv
  mfma_gemm_kernel<0><<<dim3(9, 512), 256, 0, stream>>>(
      ln_sp, wqkv, qkv_b, nullptr, nullptr, qkvb, M, 576, 192);
  // 6. natten (1 px/lane, 4 waves/block)
  natten_kernel<<<256, 256, 0, stream>>>(qkvb, rpb, obuf);
  // 7. proj + residual(xs_sp)
  mfma_gemm_kernel<1><<<dim3(3, 512), 256, 0, stream>>>(
      obuf, wproj, proj_b, xs_sp, nullptr, ybuf, M, 192, 192);
  // 8. fc2 + residual(x) + permuted scatter (swapped-operand, coalesced)
  mfma_gemm_kernel<2><<<dim3(12, 512), 256, 0, stream>>>(
      ybuf, wfc2, fc2_b, nullptr, x, (void*)out, M, 768, 192);
}